// Round 13
// baseline (94.773 us; speedup 1.0000x reference)
//
#include <hip/hip_runtime.h>
#include <hip/hip_bf16.h>

#define N_Q   25000
#define M_S   25000
#define C_INV 128

typedef unsigned short ushortT;
typedef unsigned short us8 __attribute__((ext_vector_type(8)));
typedef unsigned short us4 __attribute__((ext_vector_type(4)));
typedef short s8v __attribute__((ext_vector_type(8)));
typedef float f32x4 __attribute__((ext_vector_type(4)));

#define GAS __attribute__((address_space(1)))
#define LAS __attribute__((address_space(3)))

__device__ __forceinline__ float b2f(ushortT u) {
    unsigned v = ((unsigned)u) << 16;
    return __builtin_bit_cast(float, v);
}
__device__ __forceinline__ ushortT f2b(float f) {
    __hip_bfloat16 h = __float2bfloat16(f);
    return __builtin_bit_cast(ushortT, h);
}

// ---------------- k_prep: [0,3125) convert x -> bf16 ; [3125,4149) build wfrag2 ----------------
__global__ void k_prep(const float* __restrict__ x, ushortT* __restrict__ xb,
                       const float* __restrict__ W, ushortT* __restrict__ wf) {
    if (blockIdx.x < 3125) {
        int i = blockIdx.x * 256 + threadIdx.x;
        const int n4 = (M_S * C_INV) / 4;
        if (i >= n4) return;
        float4 v = ((const float4*)x)[i];
        us4 o;
        o[0] = f2b(v.x); o[1] = f2b(v.y); o[2] = f2b(v.z); o[3] = f2b(v.w);
        ((us4*)xb)[i] = o;
    } else {
        int o = (blockIdx.x - 3125) * 256 + threadIdx.x;
        if (o >= 262144) return;                 // 2048 * 128
        int j   = o & 7;
        int l   = (o >> 3) & 63;
        int db  = (o >> 9) & 7;
        int ks  = o >> 12;                       // 0..63
        int p   = ks * 32 + ((l >> 4) * 8) + j;  // 0..2047
        int ci  = p >> 8;
        int rem = p & 255;
        int ls  = rem >> 2;
        int r   = rem & 3;
        int k   = (ls >> 4) * 4 + r;
        int c   = ci * 16 + (ls & 15);
        int d   = db * 16 + (l & 15);
        wf[o] = (k < 15) ? f2b(W[((size_t)k * 128 + c) * 128 + d]) : (ushortT)0;
    }
}

// ---------------- fallback-only: x converter + old wfrag layout ----------------
__global__ void k_convert_x(const float* __restrict__ x, ushortT* __restrict__ xb) {
    int i = blockIdx.x * 256 + threadIdx.x;
    const int n4 = (M_S * C_INV) / 4;
    if (i >= n4) return;
    float4 v = ((const float4*)x)[i];
    us4 o;
    o[0] = f2b(v.x); o[1] = f2b(v.y); o[2] = f2b(v.z); o[3] = f2b(v.w);
    ((us4*)xb)[i] = o;
}
__global__ void k_build_wfrag(const float* __restrict__ W, ushortT* __restrict__ wf) {
    int o = blockIdx.x * 256 + threadIdx.x;
    if (o >= 1920 * 128) return;
    int j  = o & 7;
    int l  = (o >> 3) & 63;
    int db = (o >> 9) & 7;
    int ks = o >> 12;
    int r  = ks * 32 + ((l >> 4) * 8) + j;
    int d  = db * 16 + (l & 15);
    wf[o] = f2b(W[r * 128 + d]);
}

// ================= K1 (r5-verified): stages A+B, register gather, fragment-major wf =================
__global__ __launch_bounds__(512, 4) void k_ab(
    const float* __restrict__ qp, const float* __restrict__ sp,
    const int* __restrict__ nb, const float* __restrict__ kp,
    const ushortT* __restrict__ xbf, ushortT* __restrict__ wf_out)
{
    __shared__ __align__(16) ushortT s_w[16 * 512];   // 16 KB fragment layout [q][(h>>3)*128 + k*8 + (h&7)]
    __shared__ int s_idx[16 * 32];                    //  2 KB

    const int t   = threadIdx.x;
    const int l   = t & 63;
    const int w   = t >> 6;          // wave 0..7
    const int blk = blockIdx.x;

    // ---- Phase A ----
    {
        const int q  = t >> 5;
        const int h  = t & 31;
        const int qg = blk * 16 + q;
        const int qc = (qg < N_Q) ? qg : (N_Q - 1);
        const float qx = qp[qc * 3 + 0], qy = qp[qc * 3 + 1], qz = qp[qc * 3 + 2];
        int idx = (qg < N_Q) ? nb[qg * 32 + h] : M_S;
        const bool valid = ((unsigned)idx < (unsigned)M_S);
        const int idc = valid ? idx : 0;
        s_idx[q * 32 + h] = idc;
        float px, py, pz;
        if (valid) { px = sp[idc * 3]; py = sp[idc * 3 + 1]; pz = sp[idc * 3 + 2]; }
        else       { px = 1e6f; py = 1e6f; pz = 1e6f; }
        const float rx = px - qx, ry = py - qy, rz = pz - qz;
        #pragma unroll
        for (int k = 0; k < 15; ++k) {
            const float dx = rx - kp[k * 3 + 0];
            const float dy = ry - kp[k * 3 + 1];
            const float dz = rz - kp[k * 3 + 2];
            const float d2 = dx * dx + dy * dy + dz * dz;
            float wv = 1.0f - sqrtf(d2) * (1.0f / 1.2f);
            wv = (wv > 0.0f) ? wv : 0.0f;
            s_w[q * 512 + (h >> 3) * 128 + k * 8 + (h & 7)] = f2b(wv);
        }
        s_w[q * 512 + (h >> 3) * 128 + 15 * 8 + (h & 7)] = 0;
    }
    __syncthreads();

    const int c0 = l & 15;
    const int hg = l >> 4;

    s8v af[2];
    int ridx[2][8];
    #pragma unroll
    for (int qi = 0; qi < 2; ++qi) {
        const int q = w * 2 + qi;
        af[qi] = *(const s8v*)(s_w + q * 512 + hg * 128 + c0 * 8);
        #pragma unroll
        for (int j = 0; j < 8; ++j)
            ridx[qi][j] = s_idx[q * 32 + hg * 8 + j];
    }

    us4* wfo = (us4*)wf_out;

    #pragma unroll
    for (int qi = 0; qi < 2; ++qi) {
        const int qrow = blk * 16 + w * 2 + qi;
        const ushortT* rp[8];
        #pragma unroll
        for (int j = 0; j < 8; ++j)
            rp[j] = xbf + (size_t)ridx[qi][j] * 128 + c0;

        us8 xr[8];   // xr[ci][j] = x[idx[hg*8+j]][ci*16 + c0]
        #pragma unroll
        for (int j = 0; j < 8; ++j) {
            #pragma unroll
            for (int ci = 0; ci < 8; ++ci)
                xr[ci][j] = rp[j][ci * 16];
        }
        #pragma unroll
        for (int ci = 0; ci < 8; ++ci) {
            f32x4 d = __builtin_amdgcn_mfma_f32_16x16x32_bf16(
                af[qi], __builtin_bit_cast(s8v, xr[ci]), (f32x4){0.f, 0.f, 0.f, 0.f}, 0, 0, 0);
            us4 o;
            o[0] = f2b(d[0]); o[1] = f2b(d[1]); o[2] = f2b(d[2]); o[3] = f2b(d[3]);
            wfo[(size_t)qrow * 512 + ci * 64 + l] = o;
        }
    }
}

// ================= K2 v10: Q-tile 32, 512 threads / 8 waves, 782 blocks, full-K =================
// Same verified staging/swizzle/fragment expressions as r12's k_gemm32; per-wave work halved
// (wave = (qg = w>>2: 16 q-rows, dg = w&3: 2 db-chunks)) so resident waves double (12 -> ~24/CU)
// and the ~200-cyc L2-hit wfrag loads are hidden.
__global__ __launch_bounds__(512, 4) void k_gemm32w(
    const ushortT* __restrict__ wf, const ushortT* __restrict__ wfrag,
    float* __restrict__ out)
{
    __shared__ __align__(16) ushortT sA[2][4096];   // 8 KB each: 32q x 128 elems (4 ks), XOR-swizzled

    const int t    = threadIdx.x;
    const int l    = t & 63;
    const int w    = t >> 6;          // 0..7
    const int tile = blockIdx.x;      // 0..781
    const int qg   = w >> 2;          // 0..1  (16-row half)
    const int n0   = (w & 3) * 2;     // 0,2,4,6

    auto stage = [&](int c4, int buf) {
        const int q    = t >> 4;      // 0..31
        const int part = t & 15;
        const ushortT* src = wf + (size_t)(tile * 32 + q) * 2048 + c4 * 128
                           + ((part ^ (q & 7)) * 8);
        __builtin_amdgcn_global_load_lds((const GAS unsigned int*)(const void*)src,
                                         (LAS unsigned int*)(void*)(&sA[buf][(size_t)t * 8]),
                                         16, 0, 0);
    };

    f32x4 a0 = {0.f,0.f,0.f,0.f}, a1 = {0.f,0.f,0.f,0.f};

    stage(0, 0);
    __syncthreads();

    for (int c4 = 0; c4 < 16; ++c4) {
        if (c4 < 15) stage(c4 + 1, (c4 + 1) & 1);
        const ushortT* A = sA[c4 & 1];
        const int q0 = qg * 16 + (l & 15);
        #pragma unroll
        for (int kk = 0; kk < 4; ++kk) {
            const int ks = c4 * 4 + kk;
            const s8v b0 = *(const s8v*)(wfrag + ((size_t)(ks * 8 + n0    ) * 64 + l) * 8);
            const s8v b1 = *(const s8v*)(wfrag + ((size_t)(ks * 8 + n0 + 1) * 64 + l) * 8);
            const int eo = kk * 32 + (l >> 4) * 8;
            const s8v av = *(const s8v*)(A + q0 * 128 + (eo ^ ((q0 & 7) * 8)));
            a0 = __builtin_amdgcn_mfma_f32_16x16x32_bf16(av, b0, a0, 0, 0, 0);
            a1 = __builtin_amdgcn_mfma_f32_16x16x32_bf16(av, b1, a1, 0, 0, 0);
        }
        __syncthreads();
    }

    #pragma unroll
    for (int r = 0; r < 4; ++r) {
        const int qa = tile * 32 + qg * 16 + (l >> 4) * 4 + r;
        const int d0 = n0 * 16 + (l & 15);
        if (qa < N_Q) {
            out[(size_t)qa * 128 + d0]      = a0[r];
            out[(size_t)qa * 128 + d0 + 16] = a1[r];
        }
    }
}

// ================= fallback: round-1 fused kernel (tiny ws) =================
__global__ __launch_bounds__(256, 2) void k_main_fb(
    const float* __restrict__ qp, const float* __restrict__ sp,
    const int* __restrict__ nb, const float* __restrict__ kp,
    const ushortT* __restrict__ xbf, const ushortT* __restrict__ wfrag,
    float* __restrict__ out)
{
    __shared__ ushortT s_w[16][32][16];
    __shared__ int s_idx[16][32];
    __shared__ __align__(16) ushortT s_wf[16][1928];

    const int t   = threadIdx.x;
    const int blk = blockIdx.x;

    {
        const int q  = t >> 4;
        const int h0 = t & 15;
        const int qg = blk * 16 + q;
        const int qc = (qg < N_Q) ? qg : 0;
        const float qx = qp[qc * 3 + 0], qy = qp[qc * 3 + 1], qz = qp[qc * 3 + 2];
        #pragma unroll
        for (int i = 0; i < 2; ++i) {
            const int h  = h0 + 16 * i;
            int idx = (qg < N_Q) ? nb[qg * 32 + h] : M_S;
            const bool valid = ((unsigned)idx < (unsigned)M_S);
            s_idx[q][h] = valid ? idx : 0;
            float px, py, pz;
            if (valid) { px = sp[idx * 3]; py = sp[idx * 3 + 1]; pz = sp[idx * 3 + 2]; }
            else       { px = 1e6f; py = 1e6f; pz = 1e6f; }
            const float rx = px - qx, ry = py - qy, rz = pz - qz;
            #pragma unroll
            for (int k = 0; k < 15; ++k) {
                const float dx = rx - kp[k * 3 + 0];
                const float dy = ry - kp[k * 3 + 1];
                const float dz = rz - kp[k * 3 + 2];
                const float d2 = dx * dx + dy * dy + dz * dz;
                float wv = 1.0f - sqrtf(d2) * (1.0f / 1.2f);
                wv = (wv > 0.0f) ? wv : 0.0f;
                s_w[q][h][k] = f2b(wv);
            }
            s_w[q][h][15] = 0;
        }
    }
    __syncthreads();

    {
        const int q  = t >> 4;
        const int c0 = (t & 15) * 8;
        float acc[15][8];
        #pragma unroll
        for (int k = 0; k < 15; ++k)
            #pragma unroll
            for (int j = 0; j < 8; ++j) acc[k][j] = 0.0f;

        int idx0 = s_idx[q][0];
        us8 xv = *(const us8*)(xbf + (size_t)idx0 * C_INV + c0);
        for (int h = 0; h < 32; ++h) {
            const us8 xc = xv;
            if (h < 31) {
                int idn = s_idx[q][h + 1];
                xv = *(const us8*)(xbf + (size_t)idn * C_INV + c0);
            }
            const us8 w0 = *(const us8*)&s_w[q][h][0];
            const us8 w1 = *(const us8*)&s_w[q][h][8];
            float xf[8];
            #pragma unroll
            for (int j = 0; j < 8; ++j) xf[j] = b2f(xc[j]);
            #pragma unroll
            for (int k = 0; k < 15; ++k) {
                const float wk = b2f((k < 8) ? w0[k] : w1[k - 8]);
                #pragma unroll
                for (int j = 0; j < 8; ++j) acc[k][j] += wk * xf[j];
            }
        }
        #pragma unroll
        for (int k = 0; k < 15; ++k) {
            us8 o;
            #pragma unroll
            for (int j = 0; j < 8; ++j) o[j] = f2b(acc[k][j]);
            *(us8*)&s_wf[q][k * C_INV + c0] = o;
        }
    }
    __syncthreads();

    {
        const int lane = t & 63;
        const int wv   = t >> 6;
        const int db0  = wv * 2;
        const int arow = lane & 15;
        const int kofs = (lane >> 4) * 8;
        f32x4 acc0 = {0.f, 0.f, 0.f, 0.f};
        f32x4 acc1 = {0.f, 0.f, 0.f, 0.f};
        #pragma unroll 4
        for (int ks = 0; ks < 60; ++ks) {
            s8v a  = *(const s8v*)&s_wf[arow][ks * 32 + kofs];
            s8v b0 = *(const s8v*)(wfrag + ((size_t)(ks * 8 + db0) * 64 + lane) * 8);
            s8v b1 = *(const s8v*)(wfrag + ((size_t)(ks * 8 + db0 + 1) * 64 + lane) * 8);
            acc0 = __builtin_amdgcn_mfma_f32_16x16x32_bf16(a, b0, acc0, 0, 0, 0);
            acc1 = __builtin_amdgcn_mfma_f32_16x16x32_bf16(a, b1, acc1, 0, 0, 0);
        }
        #pragma unroll
        for (int r = 0; r < 4; ++r) {
            const int q  = (lane >> 4) * 4 + r;
            const int qg = blk * 16 + q;
            if (qg < N_Q) {
                out[(size_t)qg * 128 + db0 * 16 + (lane & 15)]       = acc0[r];
                out[(size_t)qg * 128 + (db0 + 1) * 16 + (lane & 15)] = acc1[r];
            }
        }
    }
}

extern "C" void kernel_launch(void* const* d_in, const int* in_sizes, int n_in,
                              void* d_out, int out_size, void* d_ws, size_t ws_size,
                              hipStream_t stream) {
    const float* x  = (const float*)d_in[0];
    const float* qp = (const float*)d_in[1];
    const float* sp = (const float*)d_in[2];
    const int*   nb = (const int*)d_in[3];
    const float* kp = (const float*)d_in[4];
    const float* W  = (const float*)d_in[5];
    float* out = (float*)d_out;

    const size_t xbf_b   = (size_t)M_S * C_INV * 2;        // 6,400,000
    const size_t wfrag_b = (size_t)2048 * 128 * 2;         // 524,288
    const size_t wf_b    = (size_t)25024 * 2048 * 2;       // 102,498,304

    ushortT* xbf   = (ushortT*)d_ws;
    ushortT* wfrag = (ushortT*)((char*)d_ws + xbf_b);
    ushortT* wfbuf = (ushortT*)((char*)d_ws + xbf_b + wfrag_b);

    if (ws_size >= xbf_b + wfrag_b + wf_b) {
        k_prep<<<3125 + 1024, 256, 0, stream>>>(x, xbf, W, wfrag);
        k_ab<<<(N_Q + 15) / 16, 512, 0, stream>>>(qp, sp, nb, kp, xbf, wfbuf);
        k_gemm32w<<<(N_Q + 31) / 32, 512, 0, stream>>>(wfbuf, wfrag, out);
    } else {
        k_convert_x<<<3125, 256, 0, stream>>>(x, xbf);
        k_build_wfrag<<<960, 256, 0, stream>>>(W, wfrag);
        k_main_fb<<<(N_Q + 15) / 16, 256, 0, stream>>>(qp, sp, nb, kp, xbf, wfrag, out);
    }
}